// Round 1
// 382.981 us; speedup vs baseline: 1.1485x; 1.1485x over previous
//
#include <hip/hip_runtime.h>

typedef __attribute__((ext_vector_type(4))) int int4v;

// ---------------------------------------------------------------------------
// Kernel 0: pack int32 weights (harness passes ALL integer inputs as int32)
// into contiguous int8. w32: [N*K] int32 in [-127,127] -> w8: [N*K] int8.
// ---------------------------------------------------------------------------
__global__ __launch_bounds__(256) void pack_w_kernel(const int* __restrict__ w32,
                                                     int* __restrict__ w8,
                                                     long n4) {
    long i = (long)blockIdx.x * 256 + threadIdx.x;  // one per 4 ints
    if (i >= n4) return;
    int4v v = ((const int4v*)w32)[i];
    w8[i] = (v[0] & 0xFF) | ((v[1] & 0xFF) << 8) |
            ((v[2] & 0xFF) << 16) | ((v[3] & 0xFF) << 24);
}

// ---------------------------------------------------------------------------
// Kernel 1: dynamic per-token symmetric int8 quantization (unchanged).
// ---------------------------------------------------------------------------
template <int NCHUNK>
__global__ __launch_bounds__(256) void quant_kernel(const float* __restrict__ x,
                                                    signed char* __restrict__ xq,
                                                    float* __restrict__ xs,
                                                    int K) {
    const int t = blockIdx.x;
    const int tid = threadIdx.x;
    const float4* row = (const float4*)(x + (size_t)t * K);

    float4 v[NCHUNK];
    float amax = 0.0f;
    #pragma unroll
    for (int i = 0; i < NCHUNK; ++i) {
        float4 f = row[i * 256 + tid];
        v[i] = f;
        amax = fmaxf(amax, fmaxf(fmaxf(fabsf(f.x), fabsf(f.y)),
                                 fmaxf(fabsf(f.z), fabsf(f.w))));
    }
    #pragma unroll
    for (int off = 32; off >= 1; off >>= 1)
        amax = fmaxf(amax, __shfl_xor(amax, off, 64));
    __shared__ float red[4];
    if ((tid & 63) == 0) red[tid >> 6] = amax;
    __syncthreads();
    amax = fmaxf(fmaxf(red[0], red[1]), fmaxf(red[2], red[3]));

    const float scale = fmaxf(amax, 1e-8f) / 127.0f;
    if (tid == 0) xs[t] = scale;
    const float inv = 1.0f / scale;

    int* orow = (int*)(xq + (size_t)t * K);
    #pragma unroll
    for (int i = 0; i < NCHUNK; ++i) {
        float4 f = v[i];
        int q0 = (int)fminf(fmaxf(rintf(f.x * inv), -128.0f), 127.0f);
        int q1 = (int)fminf(fmaxf(rintf(f.y * inv), -128.0f), 127.0f);
        int q2 = (int)fminf(fmaxf(rintf(f.z * inv), -128.0f), 127.0f);
        int q3 = (int)fminf(fmaxf(rintf(f.w * inv), -128.0f), 127.0f);
        orow[i * 256 + tid] =
            (q0 & 0xFF) | ((q1 & 0xFF) << 8) | ((q2 & 0xFF) << 16) | ((q3 & 0xFF) << 24);
    }
}

// ---------------------------------------------------------------------------
// Kernel 2: int8 GEMM, 256x256 8-phase schedule (T2 LDS-XOR-swizzle +
// T3/T4 counted-vmcnt phase pipeline + T5 setprio), port of the verified
// bf16 256sq template — i8 BK=128 bytes/row is byte-identical geometry.
//
// A: [M,K] i8 (x_q), B: [N,K] i8 (packed weight_q), C: [M,N] f32.
// 512 threads = 8 waves (2M x 4N); per-wave output 128x64 = 8x4 frags of
// mfma_i32_16x16x64_i8; per K-tile (K=128) = 64 MFMA/wave, split into 4
// quadrant phases of 16 MFMA. LDS = 2 dbuf x (A 256x128 + B 256x128) = 128 KiB.
//
// Swizzle (rule 21, both-sides-or-neither): global_load_lds dest is linear;
// per-lane global SOURCE column is pre-XORed so LDS[row][c16] = G[row][c16^(row&7)];
// fragment ds_read_b128 applies the same XOR -> 8 dwords/bank = the 1024B/wave
// floor (vs 8-way conflict in the previous 64B-row layout).
//
// Staging schedule (stage-into windows verified vs reader phases):
//   ph1: A-h0(t+1)->buf1   ph2: A-h1(t+1)->buf1   (buf1-A last read prev ph7)
//   ph3: B-h0(t+2)->buf0   ph4: B-h1(t+2)->buf0   (buf0-B last read ph2)
//   ph5: A-h0(t+2)->buf0   ph6: A-h1(t+2)->buf0   (buf0-A last read ph3)
//   ph7: B-h0(t+3)->buf1   ph8: B-h1(t+3)->buf1   (buf1-B last read ph6)
// vmcnt(4) at ph4 (tile t+1 fully landed before ph5) and ph8 (tile t+2
// landed before next ph1): 4 = the 2 stages of the current + previous phase.
// Final-iteration stages wrap mod K (written after all reads, never read).
// ---------------------------------------------------------------------------
#define BM 256
#define BN 256
#define BKB 128  // K-bytes (=128 int8) per K-tile

#define MFMA_I8 __builtin_amdgcn_mfma_i32_16x16x64_i8

#define BARRIER()                       \
    do {                                \
        __builtin_amdgcn_s_barrier();   \
        asm volatile("" ::: "memory");  \
    } while (0)

#define LGKM0() asm volatile("s_waitcnt lgkmcnt(0)" ::: "memory")
#define VMCNT4() asm volatile("s_waitcnt vmcnt(4)" ::: "memory")

#define STAGE_HALF(GL, LB, ROWOFF, KK)                                        \
    do {                                                                      \
        __builtin_amdgcn_global_load_lds(                                     \
            (const __attribute__((address_space(1))) void*)(                  \
                (GL) + (size_t)(ROWOFF) * K + (KK)),                          \
            (__attribute__((address_space(3))) void*)((LB) + (ROWOFF) * BKB), \
            16, 0, 0);                                                        \
        __builtin_amdgcn_global_load_lds(                                     \
            (const __attribute__((address_space(1))) void*)(                  \
                (GL) + (size_t)((ROWOFF) + 64) * K + (KK)),                   \
            (__attribute__((address_space(3))) void*)(                        \
                (LB) + ((ROWOFF) + 64) * BKB),                                \
            16, 0, 0);                                                        \
    } while (0)

// A-fragments m..m+3 (rows MOFF*16..), both k-subtiles. RP includes row base.
#define LDA4(RP, MOFF)                                                     \
    do {                                                                   \
        af[0][0] = *(const int4v*)((RP) + ((MOFF) + 0) * 2048 + sw0);      \
        af[0][1] = *(const int4v*)((RP) + ((MOFF) + 0) * 2048 + sw1);      \
        af[1][0] = *(const int4v*)((RP) + ((MOFF) + 1) * 2048 + sw0);      \
        af[1][1] = *(const int4v*)((RP) + ((MOFF) + 1) * 2048 + sw1);      \
        af[2][0] = *(const int4v*)((RP) + ((MOFF) + 2) * 2048 + sw0);      \
        af[2][1] = *(const int4v*)((RP) + ((MOFF) + 2) * 2048 + sw1);      \
        af[3][0] = *(const int4v*)((RP) + ((MOFF) + 3) * 2048 + sw0);      \
        af[3][1] = *(const int4v*)((RP) + ((MOFF) + 3) * 2048 + sw1);      \
    } while (0)

// B-fragments NB, NB+1, both k-subtiles.
#define LDB2M(RP, NB)                                                      \
    do {                                                                   \
        bf[(NB) + 0][0] = *(const int4v*)((RP) + ((NB) + 0) * 2048 + sw0); \
        bf[(NB) + 0][1] = *(const int4v*)((RP) + ((NB) + 0) * 2048 + sw1); \
        bf[(NB) + 1][0] = *(const int4v*)((RP) + ((NB) + 1) * 2048 + sw0); \
        bf[(NB) + 1][1] = *(const int4v*)((RP) + ((NB) + 1) * 2048 + sw1); \
    } while (0)

// One C-quadrant: 4 M-frags x 2 N-frags x 2 k-subtiles = 16 MFMA.
#define QUAD(MB, NB)                                                          \
    do {                                                                      \
        _Pragma("unroll") for (int m_ = 0; m_ < 4; ++m_) {                    \
            _Pragma("unroll") for (int n_ = 0; n_ < 2; ++n_) {                \
                acc[(MB) + m_][(NB) + n_] = MFMA_I8(                          \
                    af[m_][0], bf[(NB) + n_][0], acc[(MB) + m_][(NB) + n_],   \
                    0, 0, 0);                                                 \
                acc[(MB) + m_][(NB) + n_] = MFMA_I8(                          \
                    af[m_][1], bf[(NB) + n_][1], acc[(MB) + m_][(NB) + n_],   \
                    0, 0, 0);                                                 \
            }                                                                 \
        }                                                                     \
    } while (0)

__global__ __launch_bounds__(512, 2) void gemm_i8_kernel(
    const signed char* __restrict__ A,
    const signed char* __restrict__ B,
    const float* __restrict__ xs,    // [M] per-token scale
    const float* __restrict__ wsc,   // [N] per-channel weight scale
    const float* __restrict__ bias,  // [N]
    float* __restrict__ C,
    int M, int N, int K) {
    __shared__ __align__(16) signed char lds[2][2][BM * BKB];  // 128 KiB

    const int tid = threadIdx.x;
    const int lane = tid & 63;
    const int wv = tid >> 6;    // 0..7
    const int wrow = wv >> 2;   // 0..1 -> M half (128 rows)
    const int wcol = wv & 3;    // 0..3 -> N quarter (64 cols)
    const int fr = lane & 15;   // fragment row
    const int q = lane >> 4;    // k-quad

    const int bm = blockIdx.y * BM;
    const int bn = blockIdx.x * BN;

    // Per-lane staging source: row = wv*8 + (lane>>3); 16B-chunk pre-XORed
    // with (row&7) so the linear LDS dest ends up swizzled.
    const int srow = wv * 8 + (lane >> 3);
    const int scol = ((lane & 7) ^ ((lane >> 3) & 7)) << 4;
    const signed char* gA = A + (size_t)(bm + srow) * K + scol;
    const signed char* gB = B + (size_t)(bn + srow) * K + scol;

    // Staging LDS wave bases (HW dest = base + lane*16, linear).
    signed char* wA0 = &lds[0][0][0] + wv * 1024;
    signed char* wA1 = &lds[1][0][0] + wv * 1024;
    signed char* wB0 = &lds[0][1][0] + wv * 1024;
    signed char* wB1 = &lds[1][1][0] + wv * 1024;

    // Fragment read bases; read applies the same XOR (deswizzle).
    const int rowA = (wrow * 128 + fr) * BKB;
    const int rowB = (wcol * 64 + fr) * BKB;
    const int sw0 = ((0 + q) ^ (fr & 7)) << 4;  // k-subtile 0 chunk
    const int sw1 = ((4 + q) ^ (fr & 7)) << 4;  // k-subtile 1 chunk
    const signed char* rA0 = &lds[0][0][0] + rowA;
    const signed char* rA1 = &lds[1][0][0] + rowA;
    const signed char* rB0 = &lds[0][1][0] + rowB;
    const signed char* rB1 = &lds[1][1][0] + rowB;

    int4v acc[8][4];
    const int4v zero = {0, 0, 0, 0};
    #pragma unroll
    for (int m = 0; m < 8; ++m)
        #pragma unroll
        for (int n = 0; n < 4; ++n) acc[m][n] = zero;
    int4v af[4][2], bf[4][2];

    // Prologue: tile0 (A+B) -> buf0, tile1 B -> buf1 (12 loads).
    STAGE_HALF(gA, wA0, 0, 0);
    STAGE_HALF(gA, wA0, 128, 0);
    STAGE_HALF(gB, wB0, 0, 0);
    STAGE_HALF(gB, wB0, 128, 0);
    STAGE_HALF(gB, wB1, 0, (size_t)BKB);
    STAGE_HALF(gB, wB1, 128, (size_t)BKB);
    VMCNT4();  // tile0's 8 loads landed; tile1-B (last 4) may be in flight
    BARRIER();

    const int NT = K / BKB;  // 32 K-tiles
    for (int i = 0; i < NT / 2; ++i) {
        const size_t kk1 = (size_t)(2 * i + 1) * BKB;
        int t2 = 2 * i + 2; if (t2 >= NT) t2 -= NT;  // wrap: stage-only, never read
        int t3 = 2 * i + 3; if (t3 >= NT) t3 -= NT;
        const size_t kk2 = (size_t)t2 * BKB;
        const size_t kk3 = (size_t)t3 * BKB;

        // ---- phase 1: M0-3 x N0-1 (buf0); stage A-h0(t+1)->buf1
        LDA4(rA0, 0);
        LDB2M(rB0, 0);
        STAGE_HALF(gA, wA1, 0, kk1);
        BARRIER();
        LGKM0();
        __builtin_amdgcn_s_setprio(1);
        QUAD(0, 0);
        __builtin_amdgcn_s_setprio(0);
        BARRIER();

        // ---- phase 2: M0-3 x N2-3; stage A-h1(t+1)->buf1
        LDB2M(rB0, 2);
        STAGE_HALF(gA, wA1, 128, kk1);
        BARRIER();
        LGKM0();
        __builtin_amdgcn_s_setprio(1);
        QUAD(0, 2);
        __builtin_amdgcn_s_setprio(0);
        BARRIER();

        // ---- phase 3: M4-7 x N2-3; stage B-h0(t+2)->buf0
        LDA4(rA0, 4);
        STAGE_HALF(gB, wB0, 0, kk2);
        BARRIER();
        LGKM0();
        __builtin_amdgcn_s_setprio(1);
        QUAD(4, 2);
        __builtin_amdgcn_s_setprio(0);
        BARRIER();

        // ---- phase 4: M4-7 x N0-1; stage B-h1(t+2)->buf0; counted vmcnt
        STAGE_HALF(gB, wB0, 128, kk2);
        VMCNT4();  // tile t+1 fully landed (its A: ph1/2, B: prev ph7/8)
        BARRIER();
        __builtin_amdgcn_s_setprio(1);
        QUAD(4, 0);
        __builtin_amdgcn_s_setprio(0);
        BARRIER();

        // ---- phase 5: M0-3 x N0-1 (buf1); stage A-h0(t+2)->buf0
        LDA4(rA1, 0);
        LDB2M(rB1, 0);
        STAGE_HALF(gA, wA0, 0, kk2);
        BARRIER();
        LGKM0();
        __builtin_amdgcn_s_setprio(1);
        QUAD(0, 0);
        __builtin_amdgcn_s_setprio(0);
        BARRIER();

        // ---- phase 6: M0-3 x N2-3; stage A-h1(t+2)->buf0
        LDB2M(rB1, 2);
        STAGE_HALF(gA, wA0, 128, kk2);
        BARRIER();
        LGKM0();
        __builtin_amdgcn_s_setprio(1);
        QUAD(0, 2);
        __builtin_amdgcn_s_setprio(0);
        BARRIER();

        // ---- phase 7: M4-7 x N2-3; stage B-h0(t+3)->buf1
        LDA4(rA1, 4);
        STAGE_HALF(gB, wB1, 0, kk3);
        BARRIER();
        LGKM0();
        __builtin_amdgcn_s_setprio(1);
        QUAD(4, 2);
        __builtin_amdgcn_s_setprio(0);
        BARRIER();

        // ---- phase 8: M4-7 x N0-1; stage B-h1(t+3)->buf1; counted vmcnt
        STAGE_HALF(gB, wB1, 128, kk3);
        VMCNT4();  // tile t+2 fully landed before next-iter ph1
        BARRIER();
        __builtin_amdgcn_s_setprio(1);
        QUAD(4, 0);
        __builtin_amdgcn_s_setprio(0);
        BARRIER();
    }

    // Drain outstanding (wrapped) global_load_lds before LDS goes out of scope.
    asm volatile("s_waitcnt vmcnt(0)" ::: "memory");

    // Epilogue: C/D layout col(N)=lane&15, row(M)=(lane>>4)*4+reg (m89-verified).
    const int cb = bn + wcol * 64;
    float wv4[4], bv4[4];
    #pragma unroll
    for (int n = 0; n < 4; ++n) {
        wv4[n] = wsc[cb + n * 16 + fr];
        bv4[n] = bias[cb + n * 16 + fr];
    }
    #pragma unroll
    for (int m = 0; m < 8; ++m) {
        #pragma unroll
        for (int r = 0; r < 4; ++r) {
            const int row = bm + wrow * 128 + m * 16 + q * 4 + r;
            const float s = xs[row];
            float* crow = C + (size_t)row * N + cb + fr;
            #pragma unroll
            for (int n = 0; n < 4; ++n)
                crow[n * 16] = (float)acc[m][n][r] * s * wv4[n] + bv4[n];
        }
    }
}

// ---------------------------------------------------------------------------
extern "C" void kernel_launch(void* const* d_in, const int* in_sizes, int n_in,
                              void* d_out, int out_size, void* d_ws, size_t ws_size,
                              hipStream_t stream) {
    const float* x = (const float*)d_in[0];
    const int* wq32 = (const int*)d_in[1];  // harness passes integers as int32!
    const float* wscale = (const float*)d_in[2];
    const float* bias = (const float*)d_in[3];
    float* out = (float*)d_out;

    const int d_out_dim = in_sizes[2];             // 4096 (weight_scale length)
    const int d_in_dim = in_sizes[1] / d_out_dim;  // 4096
    const int T = in_sizes[0] / d_in_dim;          // 8192 tokens

    // Workspace: [packed weights][x_q][x_scale]
    const size_t wbytes = (size_t)d_out_dim * d_in_dim;
    signed char* w8 = (signed char*)d_ws;
    signed char* xq = (signed char*)d_ws + wbytes;
    float* xscl = (float*)((char*)d_ws + wbytes + (size_t)T * d_in_dim);

    const long n4 = (long)d_out_dim * d_in_dim / 4;
    pack_w_kernel<<<(int)((n4 + 255) / 256), 256, 0, stream>>>(wq32, (int*)w8, n4);

    if (d_in_dim == 4096) {
        quant_kernel<4><<<T, 256, 0, stream>>>(x, xq, xscl, d_in_dim);
    } else {
        quant_kernel<8><<<T, 256, 0, stream>>>(x, xq, xscl, d_in_dim);
    }

    dim3 grid(d_out_dim / BN, T / BM);
    gemm_i8_kernel<<<grid, 512, 0, stream>>>(xq, w8, xscl, wscale, bias, out,
                                             T, d_out_dim, d_in_dim);
}